// Round 11
// baseline (484.725 us; speedup 1.0000x reference)
//
#include <hip/hip_runtime.h>
#include <hip/hip_cooperative_groups.h>
#include <math.h>

namespace cg = cooperative_groups;

// Problem constants (from reference)
#define NHEAD 2
#define NDIM  64
#define HD    128   // NHEAD*NDIM
#define NGRAPH 64
#define NCLS  5
#define NEG_SLOPE 0.2f
#define LDA   136   // padded LDS row stride for W tiles
#define BLK   256
#define TOTAL_CU 256

typedef __attribute__((ext_vector_type(8))) short bf16x8;
typedef __attribute__((ext_vector_type(4))) float f32x4;

static __device__ __forceinline__ unsigned short f2bf(float f) {
    unsigned int u = __float_as_uint(f);
    u = (u + 0x7fff + ((u >> 16) & 1)) >> 16;   // round-to-nearest-even
    return (unsigned short)u;
}
static __device__ __forceinline__ float bf2f(unsigned short b) {
    return __uint_as_float((unsigned int)b << 16);
}

struct MegaP {
    const float* x;
    const int*   esrc;
    const int*   edst;
    const int*   batch;
    const float *W1, *as1, *ad1, *b1;
    const float *W2, *as2, *ad2, *b2;
    const float *W3, *as3, *ad3, *b3;
    const float *W4, *as4, *ad4, *b4;
    const float *lin_w, *lin_b;
    float* out;
    int *deg, *fill, *gcount;
    float* pooled;
    int *ptr, *bsum, *csr;
    unsigned short *hbuf, *feat, *Wt;
    float *a_src, *a_dst;
    int N, E, SB;
};

// =============== shared device bodies (used by mega AND fallback) ===============

// fp32 W[k][n] -> bf16 Wt[n][k], 3 layers, grid-stride
static __device__ void prepw_body(const float* __restrict__ W2, const float* __restrict__ W3,
                                  const float* __restrict__ W4, unsigned short* __restrict__ Wt,
                                  int gtid, int nthreads) {
    for (int idx = gtid; idx < 3 * HD * HD; idx += nthreads) {
        int l = idx / (HD * HD), rem = idx % (HD * HD);
        int nn = rem >> 7, k = rem & 127;
        const float* W = (l == 0) ? W2 : (l == 1) ? W3 : W4;
        Wt[idx] = f2bf(W[k * HD + nn]);
    }
}

// layer-1: x[N,4] @ W1[4,128] -> h bf16 + alpha dots from fp32 (wave per node, stride)
static __device__ void gemm1a_body(const float* __restrict__ x, const float* __restrict__ W,
                                   const float* __restrict__ asrc, const float* __restrict__ adst,
                                   unsigned short* __restrict__ out,
                                   float* __restrict__ oas, float* __restrict__ oad,
                                   int N, int gwave, int nwaves, int lane) {
    int c0 = lane * 2;
    float2 w0 = *(const float2*)&W[c0];
    float2 w1 = *(const float2*)&W[128 + c0];
    float2 w2 = *(const float2*)&W[256 + c0];
    float2 w3 = *(const float2*)&W[384 + c0];
    float2 av = *(const float2*)&asrc[c0];
    float2 dv = *(const float2*)&adst[c0];
    for (int n = gwave; n < N; n += nwaves) {
        float4 xv = *(const float4*)&x[n * 4];
        float v0 = xv.x * w0.x + xv.y * w1.x + xv.z * w2.x + xv.w * w3.x;
        float v1 = xv.x * w0.y + xv.y * w1.y + xv.z * w2.y + xv.w * w3.y;
        unsigned int pk = (unsigned int)f2bf(v0) | ((unsigned int)f2bf(v1) << 16);
        *(unsigned int*)&out[(size_t)n * HD + c0] = pk;
        float s = v0 * av.x + v1 * av.y;
        float t = v0 * dv.x + v1 * dv.y;
        #pragma unroll
        for (int off = 16; off > 0; off >>= 1) {
            s += __shfl_xor(s, off);
            t += __shfl_xor(t, off);
        }
        if ((lane & 31) == 0) {
            int head = lane >> 5;
            oas[n * 2 + head] = s;
            oad[n * 2 + head] = t;
        }
    }
}

// MFMA GEMM: A_bf16[N,128] @ Wt -> h bf16 + fused alphas. W in LDS (staged once);
// A loaded global->reg. Block-stride over 128-row tiles.
static __device__ void gemm_body(const unsigned short* __restrict__ A,
                                 const unsigned short* __restrict__ Wt,
                                 const float* __restrict__ asrc, const float* __restrict__ adst,
                                 unsigned short* __restrict__ out,
                                 float* __restrict__ oas, float* __restrict__ oad,
                                 int N, unsigned short* Ws, int bid, int nblocks, int tid) {
    const int lane = tid & 63, w = tid >> 6;
    const int l15 = lane & 15, quad = lane >> 4;
    const int koff = quad * 8;
    // stage W rows into LDS (16B chunks)
    for (int c = tid; c < 2048; c += BLK) {
        int row = c >> 4, k8 = (c & 15) << 3;
        *(uint4*)&Ws[row * LDA + k8] = *(const uint4*)&Wt[row * HD + k8];
    }
    float av[8], dv[8];
    #pragma unroll
    for (int c = 0; c < 8; ++c) {
        av[c] = asrc[c * 16 + l15];
        dv[c] = adst[c * 16 + l15];
    }
    __syncthreads();

    const int ntiles = (N + 127) >> 7;
    for (int tile = bid; tile < ntiles; tile += nblocks) {
        const int nbase = tile * 128;
        f32x4 acc0[8], acc1[8];
        #pragma unroll
        for (int c = 0; c < 8; ++c) { acc0[c] = (f32x4)(0.f); acc1[c] = (f32x4)(0.f); }
        const int r0 = nbase + w * 32 + l15;
        const int r1 = r0 + 16;
        #pragma unroll
        for (int ks = 0; ks < 4; ++ks) {
            bf16x8 a0 = (bf16x8)(short)0, a1 = (bf16x8)(short)0;
            if (r0 < N) a0 = *(const bf16x8*)&A[(size_t)r0 * HD + ks * 32 + koff];
            if (r1 < N) a1 = *(const bf16x8*)&A[(size_t)r1 * HD + ks * 32 + koff];
            #pragma unroll
            for (int c = 0; c < 8; ++c) {
                bf16x8 b = *(const bf16x8*)&Ws[(c * 16 + l15) * LDA + ks * 32 + koff];
                acc0[c] = __builtin_amdgcn_mfma_f32_16x16x32_bf16(a0, b, acc0[c], 0, 0, 0);
                acc1[c] = __builtin_amdgcn_mfma_f32_16x16x32_bf16(a1, b, acc1[c], 0, 0, 0);
            }
        }
        // D layout: row = i*16 + quad*4 + reg, col = c*16 + l15
        #pragma unroll
        for (int i = 0; i < 2; ++i) {
            int rowb = nbase + w * 32 + i * 16 + quad * 4;
            #pragma unroll
            for (int c = 0; c < 8; ++c) {
                f32x4 v = i ? acc1[c] : acc0[c];
                int col = c * 16 + l15;
                #pragma unroll
                for (int r = 0; r < 4; ++r) {
                    int row = rowb + r;
                    if (row < N) out[(size_t)row * HD + col] = f2bf(v[r]);
                }
            }
            #pragma unroll
            for (int r = 0; r < 4; ++r) {
                float ps0 = 0.f, ps1 = 0.f, pd0 = 0.f, pd1 = 0.f;
                #pragma unroll
                for (int c = 0; c < 4; ++c) {
                    float hv = i ? acc1[c][r] : acc0[c][r];
                    ps0 += hv * av[c]; pd0 += hv * dv[c];
                }
                #pragma unroll
                for (int c = 4; c < 8; ++c) {
                    float hv = i ? acc1[c][r] : acc0[c][r];
                    ps1 += hv * av[c]; pd1 += hv * dv[c];
                }
                #pragma unroll
                for (int off = 1; off < 16; off <<= 1) {
                    ps0 += __shfl_xor(ps0, off);
                    ps1 += __shfl_xor(ps1, off);
                    pd0 += __shfl_xor(pd0, off);
                    pd1 += __shfl_xor(pd1, off);
                }
                int row = rowb + r;
                if (l15 == 0 && row < N) {
                    *(float2*)&oas[row * 2] = make_float2(ps0, ps1);
                    *(float2*)&oad[row * 2] = make_float2(pd0, pd1);
                }
            }
        }
    }
}

// fused edge-softmax + aggregation + bias + relu; wave per node (stride).
// ALL shuffles unconditional (full exec) -- exec-masked ds_bpermute returns 0.
static __device__ void agg_body(const unsigned short* __restrict__ h,
                                const float* __restrict__ oas, const float* __restrict__ oad,
                                const int* __restrict__ ptr, const int* __restrict__ csr,
                                const float* __restrict__ bias,
                                unsigned short* __restrict__ out,
                                int N, int gwave, int nwaves, int lane) {
    const int quad = lane >> 4, sub = lane & 15;
    const int hsel = sub >> 3;
    float2 b2 = *(const float2*)&bias[lane * 2];
    float4 ba = *(const float4*)&bias[sub * 8];
    float4 bb = *(const float4*)&bias[sub * 8 + 4];
    unsigned int piso = (unsigned int)f2bf(fmaxf(b2.x, 0.f)) |
                        ((unsigned int)f2bf(fmaxf(b2.y, 0.f)) << 16);

    for (int n = gwave; n < N; n += nwaves) {
        int beg = ptr[n], end = ptr[n + 1];
        if (beg == end) {   // isolated node (wave-uniform branch)
            *(unsigned int*)&out[(size_t)n * HD + lane * 2] = piso;
            continue;
        }
        float2 adn = *(const float2*)&oad[n * 2];
        float m0 = -INFINITY, m1 = -INFINITY, l0 = 0.f, l1 = 0.f;
        float acc[8];
        #pragma unroll
        for (int k = 0; k < 8; ++k) acc[k] = 0.f;

        for (int cbeg = beg; cbeg < end; cbeg += 64) {
            int cnt = min(64, end - cbeg);
            int s = 0;
            float e0 = -INFINITY, e1 = -INFINITY;
            if (lane < cnt) {
                s = csr[cbeg + lane];
                float2 as = *(const float2*)&oas[s * 2];
                e0 = as.x + adn.x; e0 = (e0 >= 0.f) ? e0 : NEG_SLOPE * e0;
                e1 = as.y + adn.y; e1 = (e1 >= 0.f) ? e1 : NEG_SLOPE * e1;
            }
            float c0 = e0, c1 = e1;
            #pragma unroll
            for (int off = 32; off > 0; off >>= 1) {
                c0 = fmaxf(c0, __shfl_xor(c0, off));
                c1 = fmaxf(c1, __shfl_xor(c1, off));
            }
            float nm0 = fmaxf(m0, c0), nm1 = fmaxf(m1, c1);
            float sc0 = __expf(m0 - nm0), sc1 = __expf(m1 - nm1);
            float p0 = (lane < cnt) ? __expf(e0 - nm0) : 0.f;
            float p1 = (lane < cnt) ? __expf(e1 - nm1) : 0.f;
            float s0 = p0, s1 = p1;
            #pragma unroll
            for (int off = 32; off > 0; off >>= 1) {
                s0 += __shfl_xor(s0, off);
                s1 += __shfl_xor(s1, off);
            }
            l0 = l0 * sc0 + s0;
            l1 = l1 * sc1 + s1;
            m0 = nm0; m1 = nm1;
            float scl = hsel ? sc1 : sc0;
            #pragma unroll
            for (int k = 0; k < 8; ++k) acc[k] *= scl;

            // 8 edges/iter (2 per quad); j<=56 so jq<=63; p from lanes>=cnt is 0
            for (int j = 0; j < cnt; j += 8) {
                int jq0 = j + quad, jq1 = j + quad + 4;
                int sa = __shfl(s, jq0);
                int sb = __shfl(s, jq1);
                float pa0 = __shfl(p0, jq0);
                float pa1 = __shfl(p1, jq0);
                float pb0 = __shfl(p0, jq1);
                float pb1 = __shfl(p1, jq1);
                float pa = hsel ? pa1 : pa0;
                float pb = hsel ? pb1 : pb0;
                uint4 hva = *(const uint4*)&h[(size_t)sa * HD + sub * 8];
                uint4 hvb = *(const uint4*)&h[(size_t)sb * HD + sub * 8];
                #pragma unroll
                for (int k = 0; k < 4; ++k) {
                    unsigned int ua = (&hva.x)[k];
                    unsigned int ub = (&hvb.x)[k];
                    acc[2 * k]     += pa * __uint_as_float(ua << 16) + pb * __uint_as_float(ub << 16);
                    acc[2 * k + 1] += pa * __uint_as_float(ua & 0xffff0000u) + pb * __uint_as_float(ub & 0xffff0000u);
                }
            }
        }
        #pragma unroll
        for (int k = 0; k < 8; ++k) {
            acc[k] += __shfl_xor(acc[k], 16);
            acc[k] += __shfl_xor(acc[k], 32);
        }
        if (quad == 0) {
            float lsel = hsel ? l1 : l0;
            float inv = 1.f / (lsel + 1e-16f);
            float o[8];
            o[0] = fmaxf(acc[0] * inv + ba.x, 0.f);
            o[1] = fmaxf(acc[1] * inv + ba.y, 0.f);
            o[2] = fmaxf(acc[2] * inv + ba.z, 0.f);
            o[3] = fmaxf(acc[3] * inv + ba.w, 0.f);
            o[4] = fmaxf(acc[4] * inv + bb.x, 0.f);
            o[5] = fmaxf(acc[5] * inv + bb.y, 0.f);
            o[6] = fmaxf(acc[6] * inv + bb.z, 0.f);
            o[7] = fmaxf(acc[7] * inv + bb.w, 0.f);
            uint4 pk;
            pk.x = (unsigned int)f2bf(o[0]) | ((unsigned int)f2bf(o[1]) << 16);
            pk.y = (unsigned int)f2bf(o[2]) | ((unsigned int)f2bf(o[3]) << 16);
            pk.z = (unsigned int)f2bf(o[4]) | ((unsigned int)f2bf(o[5]) << 16);
            pk.w = (unsigned int)f2bf(o[6]) | ((unsigned int)f2bf(o[7]) << 16);
            *(uint4*)&out[(size_t)n * HD + sub * 8] = pk;
        }
    }
}

// pooling (block-stride over 256-node tiles; batch sorted -> run-length accumulate)
static __device__ void pool_body(const unsigned short* __restrict__ feat,
                                 const int* __restrict__ batch,
                                 float* __restrict__ pooled, int* __restrict__ gcount,
                                 int N, int bid, int nblocks, int tid) {
    int ptiles = (N + 255) >> 8;
    int col = tid & 127, half = tid >> 7;
    for (int tb = bid; tb < ptiles; tb += nblocks) {
        int n0 = tb * 256 + half * 128;
        int n1 = min(n0 + 128, N);
        float acc = 0.f;
        int curg = -1, runlen = 0;
        for (int n = n0; n < n1; ++n) {
            int g = batch[n];
            if (g != curg) {
                if (curg >= 0) {
                    atomicAdd(&pooled[curg * HD + col], acc);
                    if (col == 0) atomicAdd(&gcount[curg], runlen);
                }
                acc = 0.f; runlen = 0;
                curg = g;
            }
            acc += bf2f(feat[(size_t)n * HD + col]);
            runlen++;
        }
        if (curg >= 0) {
            atomicAdd(&pooled[curg * HD + col], acc);
            if (col == 0) atomicAdd(&gcount[curg], runlen);
        }
    }
}

static __device__ void final_body(const float* __restrict__ pooled, const int* __restrict__ gcount,
                                  const float* __restrict__ lw, const float* __restrict__ lb,
                                  float* __restrict__ out, int tid) {
    if (tid < NGRAPH) {
        float cnt = fmaxf((float)gcount[tid], 1.f);
        const float* pl = pooled + tid * HD;
        #pragma unroll
        for (int c = 0; c < NCLS; ++c) {
            float sum = 0.f;
            for (int k = 0; k < HD; ++k)
                sum += pl[k] * lw[k * NCLS + c];
            float z = lb[c] + sum / cnt;
            out[tid * NCLS + c] = 1.f / (1.f + __expf(-z));
        }
    }
}

// =============== the cooperative mega-kernel (grid-size agnostic) ===============
__global__ __launch_bounds__(BLK, 4) void k_mega(MegaP p) {
    cg::grid_group grid = cg::this_grid();
    __shared__ unsigned short Ws[128 * LDA];
    __shared__ int wsum[4];
    const int tid = threadIdx.x, bid = blockIdx.x, nblocks = gridDim.x;
    const int gtid = bid * BLK + tid;
    const int nthreads = nblocks * BLK;
    const int lane = tid & 63;
    const int gwave = gtid >> 6, nwaves = nthreads >> 6;
    const int N = p.N, E = p.E;

    // phase A: weight prep + degree histogram + layer-1 GEMM/alpha
    prepw_body(p.W2, p.W3, p.W4, p.Wt, gtid, nthreads);
    for (int i = gtid; i < E; i += nthreads) atomicAdd(&p.deg[p.edst[i]], 1);
    gemm1a_body(p.x, p.W1, p.as1, p.ad1, p.hbuf, p.a_src, p.a_dst, N, gwave, nwaves, lane);
    grid.sync();

    // phase B: per-tile local scan (tiles of 2048)
    for (int tb = bid; tb < p.SB; tb += nblocks) {
        const int wid = tid >> 6;
        const int base = tb * 2048 + tid * 8;
        int v[8];
        #pragma unroll
        for (int k = 0; k < 8; ++k) {
            int i = base + k;
            v[k] = (i < N) ? p.deg[i] : 0;
        }
        #pragma unroll
        for (int k = 1; k < 8; ++k) v[k] += v[k - 1];
        int x = v[7];
        #pragma unroll
        for (int off = 1; off < 64; off <<= 1) {
            int t = __shfl_up(x, off, 64);
            if (lane >= off) x += t;
        }
        if (lane == 63) wsum[wid] = x;
        __syncthreads();
        int woff = 0;
        #pragma unroll
        for (int k = 0; k < 4; ++k) woff += (k < wid) ? wsum[k] : 0;
        int texcl = woff + x - v[7];
        #pragma unroll
        for (int k = 0; k < 8; ++k) {
            int i = base + k;
            if (i < N) p.ptr[i + 1] = texcl + v[k];
        }
        if (tid == 255) p.bsum[tb] = woff + x;
        __syncthreads();
    }
    if (bid == 0 && tid == 0) p.ptr[0] = 0;
    grid.sync();

    // phase C: exclusive scan of tile sums (one wave; SB <= 64)
    if (bid == 0 && tid < 64) {
        int v = (tid < p.SB) ? p.bsum[tid] : 0;
        int x = v;
        #pragma unroll
        for (int off = 1; off < 64; off <<= 1) {
            int t = __shfl_up(x, off, 64);
            if (tid >= off) x += t;
        }
        if (tid < p.SB) p.bsum[tid] = x - v;
    }
    grid.sync();

    // phase D: add tile offsets
    for (int tb = bid; tb < p.SB; tb += nblocks) {
        int off = p.bsum[tb];
        if (off != 0) {
            const int base = tb * 2048 + tid * 8;
            #pragma unroll
            for (int k = 0; k < 8; ++k) {
                int i = base + k;
                if (i < N) p.ptr[i + 1] += off;
            }
        }
    }
    grid.sync();

    // phase E: scatter edges into CSR
    for (int i = gtid; i < E; i += nthreads) {
        int d = p.edst[i];
        int pos = atomicAdd(&p.fill[d], 1);
        p.csr[p.ptr[d] + pos] = p.esrc[i];
    }
    grid.sync();

    // layers: agg(L) -> gemm(L+1), ping-ponging hbuf/feat
    agg_body(p.hbuf, p.a_src, p.a_dst, p.ptr, p.csr, p.b1, p.feat, N, gwave, nwaves, lane);
    grid.sync();
    gemm_body(p.feat, p.Wt, p.as2, p.ad2, p.hbuf, p.a_src, p.a_dst, N, Ws, bid, nblocks, tid);
    grid.sync();
    agg_body(p.hbuf, p.a_src, p.a_dst, p.ptr, p.csr, p.b2, p.feat, N, gwave, nwaves, lane);
    grid.sync();
    gemm_body(p.feat, p.Wt + HD * HD, p.as3, p.ad3, p.hbuf, p.a_src, p.a_dst, N, Ws, bid, nblocks, tid);
    grid.sync();
    agg_body(p.hbuf, p.a_src, p.a_dst, p.ptr, p.csr, p.b3, p.feat, N, gwave, nwaves, lane);
    grid.sync();
    gemm_body(p.feat, p.Wt + 2 * HD * HD, p.as4, p.ad4, p.hbuf, p.a_src, p.a_dst, N, Ws, bid, nblocks, tid);
    grid.sync();
    agg_body(p.hbuf, p.a_src, p.a_dst, p.ptr, p.csr, p.b4, p.feat, N, gwave, nwaves, lane);
    grid.sync();

    pool_body(p.feat, p.batch, p.pooled, p.gcount, N, bid, nblocks, tid);
    grid.sync();

    if (bid == 0) final_body(p.pooled, p.gcount, p.lin_w, p.lin_b, p.out, tid);
}

// =============== fallback kernels (round-6/9 structure, same bodies) ===============

__global__ void k_deg_prepw(const int* __restrict__ dst, int* __restrict__ deg, int E,
                            int edge_blocks,
                            const float* __restrict__ W2, const float* __restrict__ W3,
                            const float* __restrict__ W4, unsigned short* __restrict__ Wt) {
    int b = blockIdx.x;
    if (b < edge_blocks) {
        int i = b * 256 + threadIdx.x;
        if (i < E) atomicAdd(&deg[dst[i]], 1);
    } else {
        int idx = (b - edge_blocks) * 256 + threadIdx.x;
        if (idx < 3 * HD * HD) {
            int l = idx / (HD * HD), rem = idx % (HD * HD);
            int nn = rem >> 7, k = rem & 127;
            const float* W = (l == 0) ? W2 : (l == 1) ? W3 : W4;
            Wt[idx] = f2bf(W[k * HD + nn]);
        }
    }
}

__global__ __launch_bounds__(256) void k_scan_local(const int* __restrict__ deg,
                                                    int* __restrict__ ptr,
                                                    int* __restrict__ bsum, int n) {
    __shared__ int wsum[4];
    const int tid = threadIdx.x, lane = tid & 63, wid = tid >> 6;
    const int base = blockIdx.x * 2048 + tid * 8;
    int v[8];
    #pragma unroll
    for (int k = 0; k < 8; ++k) {
        int i = base + k;
        v[k] = (i < n) ? deg[i] : 0;
    }
    #pragma unroll
    for (int k = 1; k < 8; ++k) v[k] += v[k - 1];
    int x = v[7];
    #pragma unroll
    for (int off = 1; off < 64; off <<= 1) {
        int t = __shfl_up(x, off, 64);
        if (lane >= off) x += t;
    }
    if (lane == 63) wsum[wid] = x;
    __syncthreads();
    int woff = 0;
    #pragma unroll
    for (int k = 0; k < 4; ++k) woff += (k < wid) ? wsum[k] : 0;
    int texcl = woff + x - v[7];
    #pragma unroll
    for (int k = 0; k < 8; ++k) {
        int i = base + k;
        if (i < n) ptr[i + 1] = texcl + v[k];
    }
    if (tid == 255) bsum[blockIdx.x] = woff + x;
    if (blockIdx.x == 0 && tid == 0) ptr[0] = 0;
}

__global__ void k_scan_bsum(int* __restrict__ bsum, int B) {
    int lane = threadIdx.x;
    int carry = 0;
    for (int base = 0; base < B; base += 64) {
        int i = base + lane;
        int v = (i < B) ? bsum[i] : 0;
        int x = v;
        #pragma unroll
        for (int off = 1; off < 64; off <<= 1) {
            int t = __shfl_up(x, off, 64);
            if (lane >= off) x += t;
        }
        if (i < B) bsum[i] = carry + x - v;
        carry += __shfl(x, 63, 64);
    }
}

__global__ __launch_bounds__(256) void k_scan_add(int* __restrict__ ptr,
                                                  const int* __restrict__ bsum, int n) {
    int off = bsum[blockIdx.x];
    if (off == 0) return;
    const int base = blockIdx.x * 2048 + threadIdx.x * 8;
    #pragma unroll
    for (int k = 0; k < 8; ++k) {
        int i = base + k;
        if (i < n) ptr[i + 1] += off;
    }
}

__global__ void k_scatter(const int* __restrict__ src, const int* __restrict__ dst,
                          const int* __restrict__ ptr, int* __restrict__ fill,
                          int* __restrict__ csr, int E) {
    int i = blockIdx.x * blockDim.x + threadIdx.x;
    if (i < E) {
        int d = dst[i];
        int pos = atomicAdd(&fill[d], 1);
        csr[ptr[d] + pos] = src[i];
    }
}

__global__ void k_gemm1a_w(const float* x, const float* W, const float* asrc,
                           const float* adst, unsigned short* out,
                           float* oas, float* oad, int N) {
    int gwave = (blockIdx.x * blockDim.x + threadIdx.x) >> 6;
    int nwaves = (gridDim.x * blockDim.x) >> 6;
    gemm1a_body(x, W, asrc, adst, out, oas, oad, N, gwave, nwaves, threadIdx.x & 63);
}

__global__ __launch_bounds__(256) void k_gemm_w(const unsigned short* A, const unsigned short* Wt,
                                                const float* asrc, const float* adst,
                                                unsigned short* out, float* oas, float* oad, int N) {
    __shared__ unsigned short Ws[128 * LDA];
    gemm_body(A, Wt, asrc, adst, out, oas, oad, N, Ws, blockIdx.x, gridDim.x, threadIdx.x);
}

__global__ void k_agg_w(const unsigned short* h, const float* oas, const float* oad,
                        const int* ptr, const int* csr, const float* bias,
                        unsigned short* out, int N) {
    int gwave = (blockIdx.x * blockDim.x + threadIdx.x) >> 6;
    int nwaves = (gridDim.x * blockDim.x) >> 6;
    agg_body(h, oas, oad, ptr, csr, bias, out, N, gwave, nwaves, threadIdx.x & 63);
}

__global__ void k_pool_w(const unsigned short* feat, const int* batch,
                         float* pooled, int* gcount, int N) {
    pool_body(feat, batch, pooled, gcount, N, blockIdx.x, gridDim.x, threadIdx.x);
}

__global__ void k_final_w(const float* pooled, const int* gcount,
                          const float* lw, const float* lb, float* out) {
    final_body(pooled, gcount, lw, lb, out, threadIdx.x);
}

// =============== launch ===============

static inline size_t al256(size_t x) { return (x + 255) & ~(size_t)255; }

extern "C" void kernel_launch(void* const* d_in, const int* in_sizes, int n_in,
                              void* d_out, int out_size, void* d_ws, size_t ws_size,
                              hipStream_t stream) {
    const int N = in_sizes[0] / 4;   // x is [N,4]
    const int E = in_sizes[1] / 2;   // edge_index is [2,E]

    MegaP p;
    p.x     = (const float*)d_in[0];
    p.esrc  = (const int*)d_in[1];
    p.edst  = p.esrc + E;
    p.batch = (const int*)d_in[2];
    p.W1 = (const float*)d_in[3];  p.as1 = (const float*)d_in[4];
    p.ad1 = (const float*)d_in[5]; p.b1 = (const float*)d_in[6];
    p.W2 = (const float*)d_in[7];  p.as2 = (const float*)d_in[8];
    p.ad2 = (const float*)d_in[9]; p.b2 = (const float*)d_in[10];
    p.W3 = (const float*)d_in[11]; p.as3 = (const float*)d_in[12];
    p.ad3 = (const float*)d_in[13]; p.b3 = (const float*)d_in[14];
    p.W4 = (const float*)d_in[15]; p.as4 = (const float*)d_in[16];
    p.ad4 = (const float*)d_in[17]; p.b4 = (const float*)d_in[18];
    p.lin_w = (const float*)d_in[19];
    p.lin_b = (const float*)d_in[20];
    p.out = (float*)d_out;

    char* w = (char*)d_ws;
    size_t off = 0;
    auto alloc = [&](size_t bytes) -> void* {
        void* ptr_ = w + off;
        off = al256(off + bytes);
        return ptr_;
    };
    p.deg    = (int*)alloc((size_t)N * 4);
    p.fill   = (int*)alloc((size_t)N * 4);
    p.gcount = (int*)alloc((size_t)NGRAPH * 4);
    p.pooled = (float*)alloc((size_t)NGRAPH * HD * 4);
    size_t zbytes = off;
    p.ptr    = (int*)alloc((size_t)(N + 1) * 4);
    p.bsum   = (int*)alloc((size_t)1024 * 4);
    p.csr    = (int*)alloc((size_t)E * 4);
    p.hbuf   = (unsigned short*)alloc((size_t)N * HD * 2);
    p.feat   = (unsigned short*)alloc((size_t)N * HD * 2);
    p.Wt     = (unsigned short*)alloc((size_t)3 * HD * HD * 2);
    p.a_src  = (float*)alloc((size_t)N * 2 * 4);
    p.a_dst  = (float*)alloc((size_t)N * 2 * 4);
    p.N = N; p.E = E; p.SB = (N + 2047) / 2048;
    (void)ws_size; (void)n_in; (void)out_size;

    hipMemsetAsync(d_ws, 0, zbytes, stream);

    // --- try the cooperative mega-kernel with runtime-computed co-residency ---
    bool coop_ok = false;
    int occ = 0;
    if (hipOccupancyMaxActiveBlocksPerMultiprocessor(&occ, k_mega, BLK, 0) == hipSuccess
        && occ > 0) {
        int grid = occ * TOTAL_CU;
        if (grid > 4096) grid = 4096;
        void* args[] = { &p };
        coop_ok = (hipLaunchCooperativeKernel(k_mega, dim3(grid), dim3(BLK), args,
                                              0u, stream) == hipSuccess);
    }

    if (!coop_ok) {
        // --- fallback: proven multi-kernel path (round-6/9 structure) ---
        const int edge_blocks = (E + 255) / 256;
        const int prepw_blocks = (3 * HD * HD + 255) / 256;
        k_deg_prepw<<<edge_blocks + prepw_blocks, 256, 0, stream>>>(
            p.edst, p.deg, E, edge_blocks, p.W2, p.W3, p.W4, p.Wt);
        k_scan_local<<<p.SB, 256, 0, stream>>>(p.deg, p.ptr, p.bsum, N);
        k_scan_bsum<<<1, 64, 0, stream>>>(p.bsum, p.SB);
        k_scan_add<<<p.SB, 256, 0, stream>>>(p.ptr, p.bsum, N);
        k_scatter<<<edge_blocks, 256, 0, stream>>>(p.esrc, p.edst, p.ptr, p.fill, p.csr, E);

        const int node_wave_blocks = (N + 3) / 4;
        const float* asr[4] = {p.as1, p.as2, p.as3, p.as4};
        const float* ads[4] = {p.ad1, p.ad2, p.ad3, p.ad4};
        const float* bs[4]  = {p.b1, p.b2, p.b3, p.b4};
        unsigned short* bufs[2] = {p.hbuf, p.feat};
        for (int layer = 0; layer < 4; ++layer) {
            unsigned short* hin  = bufs[0];
            unsigned short* hout = bufs[1];
            if (layer == 0) {
                k_gemm1a_w<<<node_wave_blocks, 256, 0, stream>>>(
                    p.x, p.W1, asr[0], ads[0], hin, p.a_src, p.a_dst, N);
            } else {
                k_gemm_w<<<(N + 127) / 128, 256, 0, stream>>>(
                    hout, p.Wt + (size_t)(layer - 1) * HD * HD,
                    asr[layer], ads[layer], hin, p.a_src, p.a_dst, N);
            }
            k_agg_w<<<node_wave_blocks, 256, 0, stream>>>(
                hin, p.a_src, p.a_dst, p.ptr, p.csr, bs[layer], hout, N);
        }
        k_pool_w<<<(N + 255) / 256, 256, 0, stream>>>(p.feat, p.batch, p.pooled, p.gcount, N);
        k_final_w<<<1, 64, 0, stream>>>(p.pooled, p.gcount, p.lin_w, p.lin_b, p.out);
    }
}